// Round 1
// baseline (427.621 us; speedup 1.0000x reference)
//
#include <hip/hip_runtime.h>
#include <math.h>

#define PTS_PER_BLOCK 256
#define NH 50  // 2*(L+1)^2 for L=4

// Normalization constants N(l,m) = sqrt((2l+1)/(4pi) * (l-m)!/(l+m)!)
#define N00 0.28209479177387814f
#define N10 0.4886025119029199f
#define N11 0.34549414947133547f
#define N20 0.6307831305050401f
#define N21 0.2575161346821977f
#define N22 0.12875806734109884f
#define N30 0.7463526651802308f
#define N31 0.2154534560761004f
#define N32 0.06813236509610091f
#define N33 0.02781492157551894f
#define N40 0.8462843753216345f
#define N41 0.18923493915151202f
#define N42 0.04460301380579704f
#define N43 0.011920680675223072f
#define N44 0.004214597070904597f

__global__ __launch_bounds__(PTS_PER_BLOCK) void sh_embed_kernel(
    const float* __restrict__ dirs, float* __restrict__ out, int npts) {
    __shared__ float lds[PTS_PER_BLOCK * NH];  // 50 KB

    const int tid = threadIdx.x;
    const int block_base = blockIdx.x * PTS_PER_BLOCK;
    const int pt = block_base + tid;

    float x = 0.f, y = 0.f, z = 0.f;
    if (pt < npts) {
        const float* p = dirs + (size_t)pt * 3;
        x = p[0];
        y = p[1];
        z = p[2];
    }

    // cos(theta), sin(theta) exactly as reference
    float ct = fminf(fmaxf(z, -1.f), 1.f);
    float st2 = fminf(fmaxf(1.f - ct * ct, 0.f), 1.f);
    float st = sqrtf(st2);

    // cos(phi), sin(phi) without atan2: phi = atan2(y, x)
    float rxy2 = x * x + y * y;
    float c1, s1;
    if (rxy2 > 0.f) {
        float inv = rsqrtf(rxy2);
        c1 = x * inv;
        s1 = y * inv;
    } else {
        c1 = 1.f;  // atan2(0,0) = 0
        s1 = 0.f;
    }
    // Chebyshev multiples
    float c2 = c1 * c1 - s1 * s1;
    float s2 = 2.f * c1 * s1;
    float c3 = c2 * c1 - s2 * s1;
    float s3 = s2 * c1 + c2 * s1;
    float c4 = c3 * c1 - s3 * s1;
    float s4 = s3 * c1 + c3 * s1;

    // Associated Legendre, L=4, Condon-Shortley phase (matches reference recurrences)
    float P10 = ct;
    float P11 = -st;
    float P20 = 1.5f * ct * ct - 0.5f;
    float P21 = -3.f * ct * st;
    float P22 = 3.f * st2;
    float P30 = (5.f * ct * P20 - 2.f * P10) * (1.f / 3.f);
    float P31 = (5.f * ct * P21 - 3.f * P11) * 0.5f;
    float P32 = 15.f * ct * st2;
    float P33 = -15.f * st2 * st;
    float P40 = (7.f * ct * P30 - 3.f * P20) * 0.25f;
    float P41 = (7.f * ct * P31 - 4.f * P21) * (1.f / 3.f);
    float P42 = (7.f * ct * P32 - 5.f * P22) * 0.5f;
    float P43 = -105.f * ct * st2 * st;
    float P44 = 105.f * st2 * st2;

    float v[NH];
    // l=0
    v[0] = N00;
    v[1] = 0.f;
    // l=1
    {
        float B = N11 * P11;
        float r = B * c1, i = B * s1;
        v[2] = -r; v[3] = i;        // m=-1: s=(-1)^1=-1 -> (-r, +i)
        v[4] = N10 * P10; v[5] = 0.f;
        v[6] = r; v[7] = i;
    }
    // l=2
    {
        float B2 = N22 * P22, B1 = N21 * P21;
        float r2 = B2 * c2, i2 = B2 * s2;
        float r1 = B1 * c1, i1 = B1 * s1;
        v[8] = r2;  v[9] = -i2;     // m=-2: s=+1 -> (r, -i)
        v[10] = -r1; v[11] = i1;    // m=-1
        v[12] = N20 * P20; v[13] = 0.f;
        v[14] = r1; v[15] = i1;
        v[16] = r2; v[17] = i2;
    }
    // l=3
    {
        float B3 = N33 * P33, B2 = N32 * P32, B1 = N31 * P31;
        float r3 = B3 * c3, i3 = B3 * s3;
        float r2 = B2 * c2, i2 = B2 * s2;
        float r1 = B1 * c1, i1 = B1 * s1;
        v[18] = -r3; v[19] = i3;    // m=-3: s=-1
        v[20] = r2;  v[21] = -i2;   // m=-2: s=+1
        v[22] = -r1; v[23] = i1;    // m=-1
        v[24] = N30 * P30; v[25] = 0.f;
        v[26] = r1; v[27] = i1;
        v[28] = r2; v[29] = i2;
        v[30] = r3; v[31] = i3;
    }
    // l=4
    {
        float B4 = N44 * P44, B3 = N43 * P43, B2 = N42 * P42, B1 = N41 * P41;
        float r4 = B4 * c4, i4 = B4 * s4;
        float r3 = B3 * c3, i3 = B3 * s3;
        float r2 = B2 * c2, i2 = B2 * s2;
        float r1 = B1 * c1, i1 = B1 * s1;
        v[32] = r4;  v[33] = -i4;   // m=-4: s=+1
        v[34] = -r3; v[35] = i3;    // m=-3: s=-1
        v[36] = r2;  v[37] = -i2;   // m=-2
        v[38] = -r1; v[39] = i1;    // m=-1
        v[40] = N40 * P40; v[41] = 0.f;
        v[42] = r1; v[43] = i1;
        v[44] = r2; v[45] = i2;
        v[46] = r3; v[47] = i3;
        v[48] = r4; v[49] = i4;
    }

    // Stage to LDS (row layout, float2 writes; base tid*200B is 8B-aligned)
    {
        float2* row = (float2*)&lds[tid * NH];
#pragma unroll
        for (int k = 0; k < NH / 2; ++k) {
            row[k] = make_float2(v[2 * k], v[2 * k + 1]);
        }
    }
    __syncthreads();

    // Coalesced writeback
    int valid_pts = npts - block_base;
    if (valid_pts >= PTS_PER_BLOCK) {
        // full block: float4 linear copy (12800 floats = 3200 float4)
        const float4* lds4 = (const float4*)lds;
        float4* out4 = (float4*)(out + (size_t)block_base * NH);
#pragma unroll 2
        for (int i = tid; i < PTS_PER_BLOCK * NH / 4; i += PTS_PER_BLOCK) {
            out4[i] = lds4[i];
        }
    } else if (valid_pts > 0) {
        float* outp = out + (size_t)block_base * NH;
        int n = valid_pts * NH;
        for (int i = tid; i < n; i += PTS_PER_BLOCK) {
            outp[i] = lds[i];
        }
    }
}

extern "C" void kernel_launch(void* const* d_in, const int* in_sizes, int n_in,
                              void* d_out, int out_size, void* d_ws, size_t ws_size,
                              hipStream_t stream) {
    const float* dirs = (const float*)d_in[0];
    float* out = (float*)d_out;
    int npts = in_sizes[0] / 3;
    int nblocks = (npts + PTS_PER_BLOCK - 1) / PTS_PER_BLOCK;
    sh_embed_kernel<<<dim3(nblocks), dim3(PTS_PER_BLOCK), 0, stream>>>(dirs, out, npts);
}

// Round 3
// 419.245 us; speedup vs baseline: 1.0200x; 1.0200x over previous
//
#include <hip/hip_runtime.h>
#include <math.h>

#define WAVE 64
#define NH 50  // 2*(L+1)^2 for L=4

typedef float f32x4 __attribute__((ext_vector_type(4)));  // clang vector: OK for nontemporal builtins

// Normalization constants N(l,m) = sqrt((2l+1)/(4pi) * (l-m)!/(l+m)!)
#define N00 0.28209479177387814f
#define N10 0.4886025119029199f
#define N11 0.34549414947133547f
#define N20 0.6307831305050401f
#define N21 0.2575161346821977f
#define N22 0.12875806734109884f
#define N30 0.7463526651802308f
#define N31 0.2154534560761004f
#define N32 0.06813236509610091f
#define N33 0.02781492157551894f
#define N40 0.8462843753216345f
#define N41 0.18923493915151202f
#define N42 0.04460301380579704f
#define N43 0.011920680675223072f
#define N44 0.004214597070904597f

// Single-wave workgroup: 64 pts/block, 12.8 KB LDS -> 12 blocks/CU (LDS-limited),
// __syncthreads couples only this wave (near-free barrier), blocks fully independent.
__global__ __launch_bounds__(WAVE) void sh_embed_kernel(
    const float* __restrict__ dirs, float* __restrict__ out, int npts) {
    __shared__ float lds[WAVE * NH];  // 12.8 KB

    const int lane = threadIdx.x;
    const int base_pt = blockIdx.x * WAVE;
    const int pt = base_pt + lane;

    float x = 0.f, y = 0.f, z = 0.f;
    if (pt < npts) {
        const float* p = dirs + (size_t)pt * 3;
        x = p[0];
        y = p[1];
        z = p[2];
    }

    // cos(theta), sin(theta) exactly as reference
    float ct = fminf(fmaxf(z, -1.f), 1.f);
    float st2 = fminf(fmaxf(1.f - ct * ct, 0.f), 1.f);
    float st = sqrtf(st2);

    // cos(phi), sin(phi) without atan2: phi = atan2(y, x)
    float rxy2 = x * x + y * y;
    float c1, s1;
    if (rxy2 > 0.f) {
        float inv = rsqrtf(rxy2);
        c1 = x * inv;
        s1 = y * inv;
    } else {
        c1 = 1.f;  // atan2(0,0) = 0
        s1 = 0.f;
    }
    // Chebyshev multiples
    float c2 = c1 * c1 - s1 * s1;
    float s2 = 2.f * c1 * s1;
    float c3 = c2 * c1 - s2 * s1;
    float s3 = s2 * c1 + c2 * s1;
    float c4 = c3 * c1 - s3 * s1;
    float s4 = s3 * c1 + c3 * s1;

    // Associated Legendre, L=4, Condon-Shortley phase (matches reference recurrences)
    float P10 = ct;
    float P11 = -st;
    float P20 = 1.5f * ct * ct - 0.5f;
    float P21 = -3.f * ct * st;
    float P22 = 3.f * st2;
    float P30 = (5.f * ct * P20 - 2.f * P10) * (1.f / 3.f);
    float P31 = (5.f * ct * P21 - 3.f * P11) * 0.5f;
    float P32 = 15.f * ct * st2;
    float P33 = -15.f * st2 * st;
    float P40 = (7.f * ct * P30 - 3.f * P20) * 0.25f;
    float P41 = (7.f * ct * P31 - 4.f * P21) * (1.f / 3.f);
    float P42 = (7.f * ct * P32 - 5.f * P22) * 0.5f;
    float P43 = -105.f * ct * st2 * st;
    float P44 = 105.f * st2 * st2;

    float v[NH];
    // l=0
    v[0] = N00;
    v[1] = 0.f;
    // l=1
    {
        float B = N11 * P11;
        float r = B * c1, i = B * s1;
        v[2] = -r; v[3] = i;        // m=-1: s=(-1)^1=-1 -> (-r, +i)
        v[4] = N10 * P10; v[5] = 0.f;
        v[6] = r; v[7] = i;
    }
    // l=2
    {
        float B2 = N22 * P22, B1 = N21 * P21;
        float r2 = B2 * c2, i2 = B2 * s2;
        float r1 = B1 * c1, i1 = B1 * s1;
        v[8] = r2;  v[9] = -i2;     // m=-2: s=+1 -> (r, -i)
        v[10] = -r1; v[11] = i1;    // m=-1
        v[12] = N20 * P20; v[13] = 0.f;
        v[14] = r1; v[15] = i1;
        v[16] = r2; v[17] = i2;
    }
    // l=3
    {
        float B3 = N33 * P33, B2 = N32 * P32, B1 = N31 * P31;
        float r3 = B3 * c3, i3 = B3 * s3;
        float r2 = B2 * c2, i2 = B2 * s2;
        float r1 = B1 * c1, i1 = B1 * s1;
        v[18] = -r3; v[19] = i3;    // m=-3: s=-1
        v[20] = r2;  v[21] = -i2;   // m=-2: s=+1
        v[22] = -r1; v[23] = i1;    // m=-1
        v[24] = N30 * P30; v[25] = 0.f;
        v[26] = r1; v[27] = i1;
        v[28] = r2; v[29] = i2;
        v[30] = r3; v[31] = i3;
    }
    // l=4
    {
        float B4 = N44 * P44, B3 = N43 * P43, B2 = N42 * P42, B1 = N41 * P41;
        float r4 = B4 * c4, i4 = B4 * s4;
        float r3 = B3 * c3, i3 = B3 * s3;
        float r2 = B2 * c2, i2 = B2 * s2;
        float r1 = B1 * c1, i1 = B1 * s1;
        v[32] = r4;  v[33] = -i4;   // m=-4: s=+1
        v[34] = -r3; v[35] = i3;    // m=-3: s=-1
        v[36] = r2;  v[37] = -i2;   // m=-2
        v[38] = -r1; v[39] = i1;    // m=-1
        v[40] = N40 * P40; v[41] = 0.f;
        v[42] = r1; v[43] = i1;
        v[44] = r2; v[45] = i2;
        v[46] = r3; v[47] = i3;
        v[48] = r4; v[49] = i4;
    }

    // Stage to LDS (row layout; stride 50 dwords -> 4-way write conflict, accepted:
    // padding to 51 would break the float4 linear readback below)
    {
        float2* row = (float2*)&lds[lane * NH];
#pragma unroll
        for (int k = 0; k < NH / 2; ++k) {
            row[k] = make_float2(v[2 * k], v[2 * k + 1]);
        }
    }
    __syncthreads();  // single-wave block: compiler waitcnt + near-free barrier

    // Coalesced nontemporal writeback: 64*50 floats = 800 float4, 12.5/lane
    int valid_pts = npts - base_pt;
    if (valid_pts >= WAVE) {
        const f32x4* lds4 = (const f32x4*)lds;
        f32x4* out4 = (f32x4*)(out + (size_t)base_pt * NH);
#pragma unroll
        for (int k = 0; k < 12; ++k) {
            __builtin_nontemporal_store(lds4[k * WAVE + lane], &out4[k * WAVE + lane]);
        }
        if (lane < 32) {
            __builtin_nontemporal_store(lds4[12 * WAVE + lane], &out4[12 * WAVE + lane]);
        }
    } else if (valid_pts > 0) {
        float* outp = out + (size_t)base_pt * NH;
        int n = valid_pts * NH;
        for (int i = lane; i < n; i += WAVE) {
            outp[i] = lds[i];
        }
    }
}

extern "C" void kernel_launch(void* const* d_in, const int* in_sizes, int n_in,
                              void* d_out, int out_size, void* d_ws, size_t ws_size,
                              hipStream_t stream) {
    const float* dirs = (const float*)d_in[0];
    float* out = (float*)d_out;
    int npts = in_sizes[0] / 3;
    int nblocks = (npts + WAVE - 1) / WAVE;
    sh_embed_kernel<<<dim3(nblocks), dim3(WAVE), 0, stream>>>(dirs, out, npts);
}